// Round 14
// baseline (138.887 us; speedup 1.0000x reference)
//
#include <hip/hip_runtime.h>

// SAGEConv: out = (mean_{j in N(i)} x_j) @ W_l + b_l + x_i @ W_r
// Inputs: x [N,128] f32, edge_index [2,E] int32, W_l [128,128] f32, b_l [128] f32, W_r [128,128] f32
// Output: [N,128] f32
//
// Path A (6 launches): zero_cnt -> conv_hist (dst histogram || x->bf16 ||
//   x->int8 per-row-scaled || W^T bf16) -> scan -> add_offsets -> csr_fill ->
//   sage_fused (int8 gather-mean with 16-deep index-preload + bf16 MFMA,
//   register-resident B).
// Fallbacks: B (fp32 gather + convert-in-GEMM, LDS-B), C (atomic scatter).

constexpr int N_NODES = 100000;
constexpr int N_EDGES = 625000;
constexpr int D = 128;
constexpr int SCAN_CHUNK = 1024;
constexpr int N_SCAN_BLOCKS = (N_NODES + SCAN_CHUNK - 1) / SCAN_CHUNK;  // 98
constexpr int CONV2_BLOCKS = N_NODES / 16;                              // 6250 (16 rows/block)
constexpr int E4 = N_EDGES / 4;                                         // 156250 exact
constexpr int HIST_BLOCKS = (E4 + 255) / 256;                           // 611

typedef __attribute__((ext_vector_type(8))) short short8;
typedef __attribute__((ext_vector_type(4))) short short4v;
typedef __attribute__((ext_vector_type(4))) float f32x4;

__device__ __forceinline__ unsigned short f2bf(float f) {
    union { float f; unsigned int u; } c; c.f = f;
    unsigned int u = c.u + 0x7fffu + ((c.u >> 16) & 1u);   // RNE
    return (unsigned short)(u >> 16);
}
__device__ __forceinline__ uint2 pack4(float4 a) {
    uint2 r;
    r.x = (unsigned)f2bf(a.x) | ((unsigned)f2bf(a.y) << 16);
    r.y = (unsigned)f2bf(a.z) | ((unsigned)f2bf(a.w) << 16);
    return r;
}
__device__ __forceinline__ void i8x4_to_f32(unsigned q, float* o) {
    o[0] = (float)(int)(signed char)(q & 0xff);
    o[1] = (float)(int)(signed char)((q >> 8) & 0xff);
    o[2] = (float)(int)(signed char)((q >> 16) & 0xff);
    o[3] = (float)(int)(signed char)(q >> 24);
}

// ================= zero cnt =================
__global__ __launch_bounds__(256) void zero_cnt(int* __restrict__ cnt)
{
    int i = blockIdx.x * 256 + threadIdx.x;    // uint4 index; N/4 = 25000 exact
    if (i < N_NODES / 4) ((uint4*)cnt)[i] = make_uint4(0, 0, 0, 0);
}

// ====== fused: histogram || x->bf16+int8 || W^T (all independent) ======
__global__ __launch_bounds__(256) void conv_hist(
    const float* __restrict__ x, const float* __restrict__ Wl,
    const float* __restrict__ Wr, const int* __restrict__ dst,
    unsigned short* __restrict__ xb, unsigned char* __restrict__ x8,
    float* __restrict__ scales,
    unsigned short* __restrict__ wT, int* __restrict__ cnt)
{
    const int tid = threadIdx.x;
    if (blockIdx.x < HIST_BLOCKS) {
        int t = blockIdx.x * 256 + tid;
        if (t < E4) {
            int e = t * 4;
            int4 d4 = *(const int4*)&dst[e];
            atomicAdd(&cnt[d4.x], 1);
            atomicAdd(&cnt[d4.y], 1);
            atomicAdd(&cnt[d4.z], 1);
            atomicAdd(&cnt[d4.w], 1);
        }
    } else if (blockIdx.x < HIST_BLOCKS + CONV2_BLOCKS) {
        const int cb = blockIdx.x - HIST_BLOCKS;
        const int g = tid >> 4;          // row in block
        const int l = tid & 15;
        const int row = cb * 16 + g;
        const float4* xp = (const float4*)x;
        const int f4a = row * 32 + l;
        const int f4b = f4a + 16;
        float4 v0 = xp[f4a];
        float4 v1 = xp[f4b];
        float m = fmaxf(fmaxf(fmaxf(fabsf(v0.x), fabsf(v0.y)), fmaxf(fabsf(v0.z), fabsf(v0.w))),
                        fmaxf(fmaxf(fabsf(v1.x), fabsf(v1.y)), fmaxf(fabsf(v1.z), fabsf(v1.w))));
        #pragma unroll
        for (int off = 1; off < 16; off <<= 1)
            m = fmaxf(m, __shfl_xor(m, off, 16));
        const float s   = m * (1.0f / 127.0f);
        const float inv = (m > 0.0f) ? 127.0f / m : 0.0f;
        if (l == 0) scales[row] = s;
        auto q4 = [&](float4 v) -> unsigned {
            int a0 = (int)rintf(v.x * inv);
            int a1 = (int)rintf(v.y * inv);
            int a2 = (int)rintf(v.z * inv);
            int a3 = (int)rintf(v.w * inv);
            return (unsigned)(a0 & 0xff) | ((unsigned)(a1 & 0xff) << 8) |
                   ((unsigned)(a2 & 0xff) << 16) | ((unsigned)(a3 & 0xff) << 24);
        };
        ((unsigned*)x8)[f4a] = q4(v0);
        ((unsigned*)x8)[f4b] = q4(v1);
        ((uint2*)xb)[f4a] = pack4(v0);
        ((uint2*)xb)[f4b] = pack4(v1);
    } else {
        int flat = (blockIdx.x - HIST_BLOCKS - CONV2_BLOCKS) * 256 + tid;   // 0..4095
        int k  = flat >> 4;
        int n0 = (flat & 15) * 8;
        const float* Wsrc = (k < 128) ? &Wl[k * 128 + n0] : &Wr[(k - 128) * 128 + n0];
        float4 a = *(const float4*)Wsrc;
        float4 b = *(const float4*)(Wsrc + 4);
        wT[(n0 + 0) * 256 + k] = f2bf(a.x);
        wT[(n0 + 1) * 256 + k] = f2bf(a.y);
        wT[(n0 + 2) * 256 + k] = f2bf(a.z);
        wT[(n0 + 3) * 256 + k] = f2bf(a.w);
        wT[(n0 + 4) * 256 + k] = f2bf(b.x);
        wT[(n0 + 5) * 256 + k] = f2bf(b.y);
        wT[(n0 + 6) * 256 + k] = f2bf(b.z);
        wT[(n0 + 7) * 256 + k] = f2bf(b.w);
    }
}

// standalone histogram (Path B)
__global__ __launch_bounds__(256) void hist4(
    const int* __restrict__ dst, int* __restrict__ cnt)
{
    int t = blockIdx.x * 256 + threadIdx.x;
    if (t < E4) {
        int e = t * 4;
        int4 d4 = *(const int4*)&dst[e];
        atomicAdd(&cnt[d4.x], 1);
        atomicAdd(&cnt[d4.y], 1);
        atomicAdd(&cnt[d4.z], 1);
        atomicAdd(&cnt[d4.w], 1);
    }
}

// ================= CSR scan / offsets / fill =================
__global__ __launch_bounds__(256) void scan_blocks(
    const int* __restrict__ cnt, int* __restrict__ ptr, int* __restrict__ bsums)
{
    __shared__ int sh[256];
    const int t = threadIdx.x;
    const int base = blockIdx.x * SCAN_CHUNK + t * 4;
    int v0 = (base + 0 < N_NODES) ? cnt[base + 0] : 0;
    int v1 = (base + 1 < N_NODES) ? cnt[base + 1] : 0;
    int v2 = (base + 2 < N_NODES) ? cnt[base + 2] : 0;
    int v3 = (base + 3 < N_NODES) ? cnt[base + 3] : 0;
    const int tsum = v0 + v1 + v2 + v3;
    sh[t] = tsum;
    __syncthreads();
    #pragma unroll
    for (int off = 1; off < 256; off <<= 1) {
        int val = (t >= off) ? sh[t - off] : 0;
        __syncthreads();
        sh[t] += val;
        __syncthreads();
    }
    const int texcl = sh[t] - tsum;
    if (t == 255) bsums[blockIdx.x] = sh[255];
    int e0 = texcl, e1 = e0 + v0, e2 = e1 + v1, e3 = e2 + v2;
    if (base + 0 < N_NODES) ptr[base + 0] = e0;
    if (base + 1 < N_NODES) ptr[base + 1] = e1;
    if (base + 2 < N_NODES) ptr[base + 2] = e2;
    if (base + 3 < N_NODES) ptr[base + 3] = e3;
}

__global__ __launch_bounds__(256) void add_offsets_fused(
    int* __restrict__ ptr, int* __restrict__ cursor, const int* __restrict__ bsums)
{
    __shared__ int sh[256];
    const int t = threadIdx.x;
    int v = (t < blockIdx.x) ? bsums[t] : 0;   // blockIdx.x <= 97 < 256
    sh[t] = v;
    __syncthreads();
    #pragma unroll
    for (int off = 128; off > 0; off >>= 1) {
        if (t < off) sh[t] += sh[t + off];
        __syncthreads();
    }
    const int soff = sh[0];
    const int base = blockIdx.x * SCAN_CHUNK + t * 4;
    #pragma unroll
    for (int j = 0; j < 4; ++j) {
        int i = base + j;
        if (i < N_NODES) {
            int p = ptr[i] + soff;
            ptr[i] = p;
            cursor[i] = p;
        }
    }
    if (blockIdx.x == 0 && t == 0) ptr[N_NODES] = N_EDGES;
}

__global__ __launch_bounds__(256) void csr_fill(
    const int* __restrict__ src, const int* __restrict__ dst,
    int* __restrict__ cursor, int* __restrict__ sorted_src)
{
    int t = blockIdx.x * 256 + threadIdx.x;
    if (t < E4) {
        int e = t * 4;
        int4 d4 = *(const int4*)&dst[e];
        int4 s4 = *(const int4*)&src[e];
        int p0 = atomicAdd(&cursor[d4.x], 1);
        int p1 = atomicAdd(&cursor[d4.y], 1);
        int p2 = atomicAdd(&cursor[d4.z], 1);
        int p3 = atomicAdd(&cursor[d4.w], 1);
        sorted_src[p0] = s4.x;
        sorted_src[p1] = s4.y;
        sorted_src[p2] = s4.z;
        sorted_src[p3] = s4.w;
    }
}

// ========== FUSED int8 gather-mean (16-deep preload) + bf16 MFMA ==========
// One block per 32-row tile (3125 blocks).
// Phase 1a: stage bf16 x rows into sA x-half (slots 16..31).
// Phase 1b: 8 lanes/node: 2 coalesced index loads + shfl broadcast ->
//           up to 16 predicated row loads ALL in flight -> f32 mean -> sA.
// Phase 2: MFMA (B fragments loaded after barrier) + bias + out write.
__global__ __launch_bounds__(256) void sage_fused(
    const unsigned short* __restrict__ xb,
    const unsigned char* __restrict__ x8,
    const float* __restrict__ scales,
    const int* __restrict__ ptr,
    const int* __restrict__ sorted_src,
    const unsigned short* __restrict__ wT,
    const float* __restrict__ bl,
    float* __restrict__ out)
{
    __shared__ unsigned short sA[32 * 256];   // 16 KB

    const int tid  = threadIdx.x;
    const int lane = tid & 63;
    const int w    = tid >> 6;
    const int l15  = lane & 15;
    const int lg   = lane >> 4;

    const int row0 = blockIdx.x * 32;

    // ---- phase 1a: stage x-half (slots 16..31), 2 short8 chunks/thread ----
    #pragma unroll
    for (int i = 0; i < 2; ++i) {
        int c = tid + i * 256;          // 0..511
        int r = c >> 4;                 // 32 rows x 16 chunks
        int s = 16 + (c & 15);
        short8 v = *(const short8*)&xb[(size_t)(row0 + r) * D + (c & 15) * 8];
        *(short8*)&sA[r * 256 + ((s ^ (r & 7)) << 3)] = v;
    }

    // ---- phase 1b: int8 gather-mean, 8 lanes/node, 16-deep preload ----
    {
        const int g = tid >> 3;          // 0..31 (row)
        const int l = tid & 7;
        const size_t off8 = (size_t)l * 16;   // byte offset in 128B int8 row
        const int node = row0 + g;
        const int beg = ptr[node];
        const int end = ptr[node + 1];
        const int deg = end - beg;
        const int last = (deg > 0) ? (end - 1) : 0;

        // two coalesced index loads cover the first 16 neighbors
        int ia = sorted_src[min(beg + l, last)];
        int ib = sorted_src[min(beg + 8 + l, last)];

        float acc0[16], acc1[16], acc2[16], acc3[16];
        #pragma unroll
        for (int j = 0; j < 16; ++j) { acc0[j]=0.f; acc1[j]=0.f; acc2[j]=0.f; acc3[j]=0.f; }

        // 16 predicated row loads, all independent (high MLP)
        #pragma unroll
        for (int j = 0; j < 16; ++j) {
            int sj = (j < 8) ? __shfl(ia, j, 8) : __shfl(ib, j - 8, 8);
            float wj = (j < deg) ? 1.0f : 0.0f;
            uint4 q = *(const uint4*)&x8[(size_t)sj * D + off8];
            float ws = wj * scales[sj];
            float t[16];
            i8x4_to_f32(q.x, &t[0]);  i8x4_to_f32(q.y, &t[4]);
            i8x4_to_f32(q.z, &t[8]);  i8x4_to_f32(q.w, &t[12]);
            float* A = ((j & 3) == 0) ? acc0 : ((j & 3) == 1) ? acc1
                     : ((j & 3) == 2) ? acc2 : acc3;
            #pragma unroll
            for (int k = 0; k < 16; ++k) A[k] = fmaf(ws, t[k], A[k]);
        }

        // rare tail: deg > 16 (P ~ 2e-4 for Poisson(6.25))
        for (int i = beg + 16; i < end; i += 4) {
            int e1 = i + 1 < end ? i + 1 : end - 1;
            int e2 = i + 2 < end ? i + 2 : end - 1;
            int e3 = i + 3 < end ? i + 3 : end - 1;
            float w1 = (i + 1 < end) ? 1.f : 0.f;
            float w2 = (i + 2 < end) ? 1.f : 0.f;
            float w3 = (i + 3 < end) ? 1.f : 0.f;
            int s0 = sorted_src[i],  s1 = sorted_src[e1];
            int s2 = sorted_src[e2], s3 = sorted_src[e3];
            uint4 q0 = *(const uint4*)&x8[(size_t)s0 * D + off8];
            uint4 q1 = *(const uint4*)&x8[(size_t)s1 * D + off8];
            uint4 q2 = *(const uint4*)&x8[(size_t)s2 * D + off8];
            uint4 q3 = *(const uint4*)&x8[(size_t)s3 * D + off8];
            float ws0 = scales[s0];
            float ws1 = w1 * scales[s1];
            float ws2 = w2 * scales[s2];
            float ws3 = w3 * scales[s3];
            float t[16];
            i8x4_to_f32(q0.x, &t[0]);  i8x4_to_f32(q0.y, &t[4]);
            i8x4_to_f32(q0.z, &t[8]);  i8x4_to_f32(q0.w, &t[12]);
            #pragma unroll
            for (int k = 0; k < 16; ++k) acc0[k] = fmaf(ws0, t[k], acc0[k]);
            i8x4_to_f32(q1.x, &t[0]);  i8x4_to_f32(q1.y, &t[4]);
            i8x4_to_f32(q1.z, &t[8]);  i8x4_to_f32(q1.w, &t[12]);
            #pragma unroll
            for (int k = 0; k < 16; ++k) acc1[k] = fmaf(ws1, t[k], acc1[k]);
            i8x4_to_f32(q2.x, &t[0]);  i8x4_to_f32(q2.y, &t[4]);
            i8x4_to_f32(q2.z, &t[8]);  i8x4_to_f32(q2.w, &t[12]);
            #pragma unroll
            for (int k = 0; k < 16; ++k) acc2[k] = fmaf(ws2, t[k], acc2[k]);
            i8x4_to_f32(q3.x, &t[0]);  i8x4_to_f32(q3.y, &t[4]);
            i8x4_to_f32(q3.z, &t[8]);  i8x4_to_f32(q3.w, &t[12]);
            #pragma unroll
            for (int k = 0; k < 16; ++k) acc3[k] = fmaf(ws3, t[k], acc3[k]);
        }

        const float sc = 1.0f / fmaxf((float)deg, 1.0f);
        float m[16];
        #pragma unroll
        for (int j = 0; j < 16; ++j)
            m[j] = ((acc0[j] + acc1[j]) + (acc2[j] + acc3[j])) * sc;

        uint4 o_lo, o_hi;
        o_lo.x = (unsigned)f2bf(m[0])  | ((unsigned)f2bf(m[1])  << 16);
        o_lo.y = (unsigned)f2bf(m[2])  | ((unsigned)f2bf(m[3])  << 16);
        o_lo.z = (unsigned)f2bf(m[4])  | ((unsigned)f2bf(m[5])  << 16);
        o_lo.w = (unsigned)f2bf(m[6])  | ((unsigned)f2bf(m[7])  << 16);
        o_hi.x = (unsigned)f2bf(m[8])  | ((unsigned)f2bf(m[9])  << 16);
        o_hi.y = (unsigned)f2bf(m[10]) | ((unsigned)f2bf(m[11]) << 16);
        o_hi.z = (unsigned)f2bf(m[12]) | ((unsigned)f2bf(m[13]) << 16);
        o_hi.w = (unsigned)f2bf(m[14]) | ((unsigned)f2bf(m[15]) << 16);
        int s0s = 2 * l;              // slots 0..15 (mean half)
        int s1s = 2 * l + 1;
        *(uint4*)&sA[g * 256 + ((s0s ^ (g & 7)) << 3)] = o_lo;
        *(uint4*)&sA[g * 256 + ((s1s ^ (g & 7)) << 3)] = o_hi;
    }
    __syncthreads();

    // ---- phase 2: MFMA (B loaded here to keep gather-phase VGPRs low) ----
    const int n0 = w * 32 + l15;
    const int n1 = n0 + 16;
    short8 B0[8], B1[8];
    #pragma unroll
    for (int s = 0; s < 8; ++s) {
        B0[s] = *(const short8*)&wT[(size_t)n0 * 256 + s * 32 + lg * 8];
        B1[s] = *(const short8*)&wT[(size_t)n1 * 256 + s * 32 + lg * 8];
    }
    const float bias0 = bl[n0];
    const float bias1 = bl[n1];

    const int a_r0 = l15;
    const int a_r1 = 16 + l15;

    f32x4 acc00 = {0.f,0.f,0.f,0.f}, acc01 = {0.f,0.f,0.f,0.f};
    f32x4 acc10 = {0.f,0.f,0.f,0.f}, acc11 = {0.f,0.f,0.f,0.f};

    #pragma unroll
    for (int s = 0; s < 8; ++s) {
        int ks = s * 4 + lg;
        short8 a0 = *(const short8*)&sA[a_r0 * 256 + ((ks ^ (a_r0 & 7)) << 3)];
        short8 a1 = *(const short8*)&sA[a_r1 * 256 + ((ks ^ (a_r1 & 7)) << 3)];
        acc00 = __builtin_amdgcn_mfma_f32_16x16x32_bf16(a0, B0[s], acc00, 0, 0, 0);
        acc01 = __builtin_amdgcn_mfma_f32_16x16x32_bf16(a0, B1[s], acc01, 0, 0, 0);
        acc10 = __builtin_amdgcn_mfma_f32_16x16x32_bf16(a1, B0[s], acc10, 0, 0, 0);
        acc11 = __builtin_amdgcn_mfma_f32_16x16x32_bf16(a1, B1[s], acc11, 0, 0, 0);
    }

    // C layout: col=lane&15, row=(lane>>4)*4+reg (m89)
    #pragma unroll
    for (int reg = 0; reg < 4; ++reg) {
        int r0w = row0 + lg * 4 + reg;
        int r1w = r0w + 16;
        out[(size_t)r0w * D + n0] = acc00[reg] + bias0;
        out[(size_t)r0w * D + n1] = acc01[reg] + bias1;
        out[(size_t)r1w * D + n0] = acc10[reg] + bias0;
        out[(size_t)r1w * D + n1] = acc11[reg] + bias1;
    }
}

// ================= Path B: fp32 gather + convert-in-GEMM (LDS-B) ===========
__global__ __launch_bounds__(256) void wt_build(
    const float* __restrict__ Wl, const float* __restrict__ Wr,
    unsigned short* __restrict__ wT)
{
    int idx = blockIdx.x * 256 + threadIdx.x;
    if (idx >= 128 * 256) return;
    int n = idx >> 8;
    int k = idx & 255;
    float v = (k < 128) ? Wl[k * 128 + n] : Wr[(k - 128) * 128 + n];
    wT[n * 256 + k] = f2bf(v);
}

__global__ __launch_bounds__(256) void sage_aggregate(
    const float* __restrict__ x,
    const int* __restrict__ ptr,
    const int* __restrict__ sorted_src,
    float* __restrict__ mean)
{
    const int node = blockIdx.x * 4 + (threadIdx.x >> 6);
    if (node >= N_NODES) return;
    const int lane = threadIdx.x & 63;
    const int beg = ptr[node];
    const int end = ptr[node + 1];

    float2 acc0 = make_float2(0.f, 0.f);
    float2 acc1 = make_float2(0.f, 0.f);
    int i = beg;
    for (; i + 1 < end; i += 2) {
        int s0 = sorted_src[i];
        int s1 = sorted_src[i + 1];
        float2 a = *(const float2*)&x[(size_t)s0 * D + lane * 2];
        float2 b = *(const float2*)&x[(size_t)s1 * D + lane * 2];
        acc0.x += a.x; acc0.y += a.y;
        acc1.x += b.x; acc1.y += b.y;
    }
    if (i < end) {
        int s0 = sorted_src[i];
        float2 a = *(const float2*)&x[(size_t)s0 * D + lane * 2];
        acc0.x += a.x; acc0.y += a.y;
    }
    const float sc = 1.0f / fmaxf((float)(end - beg), 1.0f);
    float2 r = make_float2((acc0.x + acc1.x) * sc, (acc0.y + acc1.y) * sc);
    *(float2*)&mean[(size_t)node * D + lane * 2] = r;
}

__global__ __launch_bounds__(256) void sage_gemm_mfma(
    const float* __restrict__ x,
    const unsigned short* __restrict__ wT,
    const float* __restrict__ bl,
    float* __restrict__ out)
{
    __shared__ unsigned short sW[128 * 256];
    __shared__ unsigned short sA1[32 * 256];

    const int tid  = threadIdx.x;
    const int lane = tid & 63;
    const int w    = tid >> 6;
    const int l15  = lane & 15;
    const int lg   = lane >> 4;

    #pragma unroll
    for (int i = 0; i < 16; ++i) {
        int c  = tid + i * 256;
        int n  = c >> 5;
        int k8 = c & 31;
        short8 v = ((const short8*)wT)[c];
        *(short8*)&sW[n * 256 + ((k8 ^ (n & 7)) << 3)] = v;
    }

    const int a_r0 = l15;
    const int a_r1 = 16 + l15;
    const int n0 = w * 32 + l15;
    const int n1 = n0 + 16;
    const float bias0 = bl[n0];
    const float bias1 = bl[n1];
    const int nTiles = N_NODES / 32;

    for (int tile = blockIdx.x; tile < nTiles; tile += gridDim.x) {
        const int row0 = tile * 32;
        #pragma unroll
        for (int i = 0; i < 8; ++i) {
            int c    = tid + i * 256;
            int r    = c >> 6;
            int half = (c >> 5) & 1;
            int f4   = c & 31;
            const float* srcp = half ? &x[(size_t)(row0 + r) * D + f4 * 4]
                                     : &out[(size_t)(row0 + r) * D + f4 * 4];
            float4 v = *(const float4*)srcp;
            short4v b;
            b.x = (short)f2bf(v.x); b.y = (short)f2bf(v.y);
            b.z = (short)f2bf(v.z); b.w = (short)f2bf(v.w);
            int k = half * 128 + f4 * 4;
            int u = k >> 3;
            *(short4v*)&sA1[r * 256 + ((u ^ (r & 7)) << 3) + (k & 7)] = b;
        }
        __syncthreads();

        f32x4 acc00 = {0.f,0.f,0.f,0.f}, acc01 = {0.f,0.f,0.f,0.f};
        f32x4 acc10 = {0.f,0.f,0.f,0.f}, acc11 = {0.f,0.f,0.f,0.f};

        #pragma unroll
        for (int s = 0; s < 8; ++s) {
            int ks = s * 4 + lg;
            short8 a0 = *(const short8*)&sA1[a_r0 * 256 + ((ks ^ (a_r0 & 7)) << 3)];
            short8 a1 = *(const short8*)&sA1[a_r1 * 256 + ((ks ^ (a_r1 & 7)) << 3)];
            short8 b0 = *(const short8*)&sW[n0 * 256 + ((ks ^ (n0 & 7)) << 3)];
            short8 b1 = *(const short8*)&sW[n1 * 256 + ((ks ^ (n1 & 7)) << 3)];
            acc00 = __builtin_amdgcn_mfma_f32_16x16x32_bf16(a0, b0, acc00, 0, 0, 0);
            acc01 = __builtin_amdgcn_mfma_f32_16x16x32_bf16(a0, b1, acc01, 0, 0, 0);
            acc10 = __builtin_amdgcn_mfma_f32_16x16x32_bf16(a1, b0, acc10, 0, 0, 0);
            acc11 = __builtin_amdgcn_mfma_f32_16x16x32_bf16(a1, b1, acc11, 0, 0, 0);
        }
        __syncthreads();

        #pragma unroll
        for (int reg = 0; reg < 4; ++reg) {
            int r0w = row0 + lg * 4 + reg;
            int r1w = r0w + 16;
            out[(size_t)r0w * D + n0] = acc00[reg] + bias0;
            out[(size_t)r0w * D + n1] = acc01[reg] + bias1;
            out[(size_t)r1w * D + n0] = acc10[reg] + bias0;
            out[(size_t)r1w * D + n1] = acc11[reg] + bias1;
        }
    }
}

// ================= Path C: scatter fallback ================================
__global__ __launch_bounds__(256) void sage_scatter(
    const float* __restrict__ x, const int* __restrict__ src,
    const int* __restrict__ dst, float* __restrict__ agg, float* __restrict__ deg)
{
    int gid = blockIdx.x * 256 + threadIdx.x;
    int e = gid >> 7;
    if (e >= N_EDGES) return;
    int d = gid & 127;
    atomicAdd(&agg[(size_t)dst[e] * D + d], x[(size_t)src[e] * D + d]);
    if (d == 0) atomicAdd(&deg[dst[e]], 1.0f);
}

__global__ __launch_bounds__(256) void apply_mean(
    float* __restrict__ agg, const float* __restrict__ deg)
{
    int gid = blockIdx.x * 256 + threadIdx.x;
    int row = gid >> 5;
    if (row >= N_NODES) return;
    float sc = 1.0f / fmaxf(deg[row], 1.0f);
    float4 v = ((float4*)agg)[gid];
    v.x *= sc; v.y *= sc; v.z *= sc; v.w *= sc;
    ((float4*)agg)[gid] = v;
}

__device__ __forceinline__ void accum_tile(
    float acc[4][4], const float (*sWf)[D], const float (*srow)[D], int h, int j4)
{
    #pragma unroll 2
    for (int k = 0; k < D; k += 4) {
        float4 w0 = *(const float4*)&sWf[k + 0][j4];
        float4 w1 = *(const float4*)&sWf[k + 1][j4];
        float4 w2 = *(const float4*)&sWf[k + 2][j4];
        float4 w3 = *(const float4*)&sWf[k + 3][j4];
        #pragma unroll
        for (int r = 0; r < 4; ++r) {
            float4 a = *(const float4*)&srow[h + r * 8][k];
            acc[r][0] = fmaf(a.x, w0.x, fmaf(a.y, w1.x, fmaf(a.z, w2.x, fmaf(a.w, w3.x, acc[r][0]))));
            acc[r][1] = fmaf(a.x, w0.y, fmaf(a.y, w1.y, fmaf(a.z, w2.y, fmaf(a.w, w3.y, acc[r][1]))));
            acc[r][2] = fmaf(a.x, w0.z, fmaf(a.y, w1.z, fmaf(a.z, w2.z, fmaf(a.w, w3.z, acc[r][2]))));
            acc[r][3] = fmaf(a.x, w0.w, fmaf(a.y, w1.w, fmaf(a.z, w2.w, fmaf(a.w, w3.w, acc[r][3]))));
        }
    }
}

__global__ __launch_bounds__(256) void sage_gemm_f32(
    const float* __restrict__ x, const float* __restrict__ Wl,
    const float* __restrict__ bl, const float* __restrict__ Wr,
    float* __restrict__ out)
{
    __shared__ float sWf[D][D];
    __shared__ float srow[32][D];
    const int tid = threadIdx.x;
    const int j4 = (tid & 31) * 4;
    const int h  = tid >> 5;
    const int nTiles = (N_NODES + 31) / 32;
    const float4 bias = *(const float4*)(bl + j4);

    for (int tile = blockIdx.x; tile < nTiles; tile += gridDim.x) {
        const int row0 = tile * 32;
        float acc[4][4];
        #pragma unroll
        for (int r = 0; r < 4; ++r)
            #pragma unroll
            for (int c = 0; c < 4; ++c) acc[r][c] = 0.0f;

        __syncthreads();
        #pragma unroll
        for (int i = 0; i < 16; ++i)
            ((float4*)sWf)[tid + i * 256] = ((const float4*)Wl)[tid + i * 256];
        #pragma unroll
        for (int i = 0; i < 4; ++i) {
            int idx = tid + i * 256, r = idx >> 5, c = idx & 31, row = row0 + r;
            float4 v = make_float4(0.f,0.f,0.f,0.f);
            if (row < N_NODES) v = ((const float4*)out)[(size_t)row * 32 + c];
            ((float4*)srow)[idx] = v;
        }
        __syncthreads();
        accum_tile(acc, sWf, srow, h, j4);

        __syncthreads();
        #pragma unroll
        for (int i = 0; i < 16; ++i)
            ((float4*)sWf)[tid + i * 256] = ((const float4*)Wr)[tid + i * 256];
        #pragma unroll
        for (int i = 0; i < 4; ++i) {
            int idx = tid + i * 256, r = idx >> 5, c = idx & 31, row = row0 + r;
            float4 v = make_float4(0.f,0.f,0.f,0.f);
            if (row < N_NODES) v = ((const float4*)x)[(size_t)row * 32 + c];
            ((float4*)srow)[idx] = v;
        }
        __syncthreads();
        accum_tile(acc, sWf, srow, h, j4);

        #pragma unroll
        for (int r = 0; r < 4; ++r) {
            int row = row0 + h + r * 8;
            if (row < N_NODES) {
                float4 v = make_float4(acc[r][0] + bias.x, acc[r][1] + bias.y,
                                       acc[r][2] + bias.z, acc[r][3] + bias.w);
                *(float4*)(out + (size_t)row * D + j4) = v;
            }
        }
    }
}

extern "C" void kernel_launch(void* const* d_in, const int* in_sizes, int n_in,
                              void* d_out, int out_size, void* d_ws, size_t ws_size,
                              hipStream_t stream) {
    const float* x   = (const float*)d_in[0];
    const int*   ei  = (const int*)d_in[1];
    const float* Wl  = (const float*)d_in[2];
    const float* bl  = (const float*)d_in[3];
    const float* Wr  = (const float*)d_in[4];
    float* out = (float*)d_out;

    const int* src = ei;
    const int* dst = ei + N_EDGES;

    int* cnt    = (int*)d_ws;                    // N
    int* ptr    = cnt + N_NODES;                 // N+1
    int* cursor = ptr + N_NODES + 1;             // N
    int* bsums  = cursor + N_NODES;              // 128
    int* sorted = bsums + 128;                   // E
    size_t int_count = (size_t)(3 * N_NODES + 1 + 128 + N_EDGES);
    int_count = (int_count + 7) & ~(size_t)7;    // 32B-align what follows
    unsigned short* wT = (unsigned short*)((int*)d_ws + int_count);  // 128*256 bf16
    unsigned short* xb = wT + 128 * 256;                             // N*D bf16
    unsigned char*  x8 = (unsigned char*)(xb + (size_t)N_NODES * D); // N*D int8
    float* scales      = (float*)(x8 + (size_t)N_NODES * D);         // N f32

    size_t need_B = int_count * sizeof(int);
    size_t need_A = need_B + 128 * 256 * 2 + (size_t)N_NODES * D * 2
                    + (size_t)N_NODES * D + (size_t)N_NODES * 4;  // wT+xb+x8+scales

    if (ws_size >= need_A) {
        zero_cnt<<<(N_NODES / 4 + 255) / 256, 256, 0, stream>>>(cnt);
        conv_hist<<<HIST_BLOCKS + CONV2_BLOCKS + 16, 256, 0, stream>>>(
            x, Wl, Wr, dst, xb, x8, scales, wT, cnt);
        scan_blocks<<<N_SCAN_BLOCKS, 256, 0, stream>>>(cnt, ptr, bsums);
        add_offsets_fused<<<N_SCAN_BLOCKS, 256, 0, stream>>>(ptr, cursor, bsums);
        csr_fill<<<(E4 + 255) / 256, 256, 0, stream>>>(src, dst, cursor, sorted);
        sage_fused<<<N_NODES / 32, 256, 0, stream>>>(
            xb, x8, scales, ptr, sorted, wT, bl, out);
    } else if (ws_size >= need_B) {
        hipMemsetAsync(cnt, 0, (size_t)N_NODES * sizeof(int), stream);
        hist4<<<(E4 + 255) / 256, 256, 0, stream>>>(dst, cnt);
        scan_blocks<<<N_SCAN_BLOCKS, 256, 0, stream>>>(cnt, ptr, bsums);
        add_offsets_fused<<<N_SCAN_BLOCKS, 256, 0, stream>>>(ptr, cursor, bsums);
        csr_fill<<<(E4 + 255) / 256, 256, 0, stream>>>(src, dst, cursor, sorted);
        unsigned short* wTc = (unsigned short*)cursor;   // cursor dead after fill
        wt_build<<<(128 * 256 + 255) / 256, 256, 0, stream>>>(Wl, Wr, wTc);
        sage_aggregate<<<(N_NODES + 3) / 4, 256, 0, stream>>>(x, ptr, sorted, out);
        sage_gemm_mfma<<<512, 256, 0, stream>>>(x, wTc, bl, out);
    } else {
        float* deg = (float*)d_ws;
        hipMemsetAsync(out, 0, (size_t)N_NODES * D * sizeof(float), stream);
        hipMemsetAsync(deg, 0, (size_t)N_NODES * sizeof(float), stream);
        long long total = (long long)N_EDGES * 128;
        sage_scatter<<<(int)((total + 255) / 256), 256, 0, stream>>>(x, src, dst, out, deg);
        apply_mean<<<(N_NODES * 32 + 255) / 256, 256, 0, stream>>>(out, deg);
        sage_gemm_f32<<<512, 256, 0, stream>>>(x, Wl, bl, Wr, out);
    }
}

// Round 15
// 133.786 us; speedup vs baseline: 1.0381x; 1.0381x over previous
//
#include <hip/hip_runtime.h>

// SAGEConv: out = (mean_{j in N(i)} x_j) @ W_l + b_l + x_i @ W_r
// Inputs: x [N,128] f32, edge_index [2,E] int32, W_l [128,128] f32, b_l [128] f32, W_r [128,128] f32
// Output: [N,128] f32
//
// Path A (6 launches): conv_all (x->bf16 + x->int8 per-row-scaled + W^T bf16 +
//   zero cnt) -> hist4 -> scan -> add_offsets -> csr_fill -> sage_fused
//   (int8 gather-mean into LDS A-tile + bf16 MFMA with register-resident B).
// [R14 note: this is the R13 configuration, reverted verbatim — 16-deep
//  preload (R14) and bigger-ILP variants regressed; 4-deep ILP is best-known.]
// Fallbacks: B (fp32 gather + convert-in-GEMM, LDS-B), C (atomic scatter).

constexpr int N_NODES = 100000;
constexpr int N_EDGES = 625000;
constexpr int D = 128;
constexpr int SCAN_CHUNK = 1024;
constexpr int N_SCAN_BLOCKS = (N_NODES + SCAN_CHUNK - 1) / SCAN_CHUNK;  // 98
constexpr int CONV2_BLOCKS = N_NODES / 16;                              // 6250 (16 rows/block)
constexpr int ZERO_BLOCKS = (N_NODES / 4 + 255) / 256;                  // 98
constexpr int E4 = N_EDGES / 4;                                         // 156250 exact

typedef __attribute__((ext_vector_type(8))) short short8;
typedef __attribute__((ext_vector_type(4))) short short4v;
typedef __attribute__((ext_vector_type(4))) float f32x4;

__device__ __forceinline__ unsigned short f2bf(float f) {
    union { float f; unsigned int u; } c; c.f = f;
    unsigned int u = c.u + 0x7fffu + ((c.u >> 16) & 1u);   // RNE
    return (unsigned short)(u >> 16);
}
__device__ __forceinline__ uint2 pack4(float4 a) {
    uint2 r;
    r.x = (unsigned)f2bf(a.x) | ((unsigned)f2bf(a.y) << 16);
    r.y = (unsigned)f2bf(a.z) | ((unsigned)f2bf(a.w) << 16);
    return r;
}
__device__ __forceinline__ void i8x4_to_f32(unsigned q, float* o) {
    o[0] = (float)(int)(signed char)(q & 0xff);
    o[1] = (float)(int)(signed char)((q >> 8) & 0xff);
    o[2] = (float)(int)(signed char)((q >> 16) & 0xff);
    o[3] = (float)(int)(signed char)(q >> 24);
}

// ====== fused prep: x->bf16 + x->int8 (per-row scale), W^T bf16, zero cnt ===
// Conv blocks: 16 lanes/row, 16 rows/block. All loads/stores dense per instr.
__global__ __launch_bounds__(256) void conv_all(
    const float* __restrict__ x, const float* __restrict__ Wl,
    const float* __restrict__ Wr,
    unsigned short* __restrict__ xb, unsigned char* __restrict__ x8,
    float* __restrict__ scales,
    unsigned short* __restrict__ wT, int* __restrict__ cnt)
{
    const int tid = threadIdx.x;
    if (blockIdx.x < CONV2_BLOCKS) {
        const int g = tid >> 4;          // row in block
        const int l = tid & 15;
        const int row = blockIdx.x * 16 + g;
        const float4* xp = (const float4*)x;
        const int f4a = row * 32 + l;
        const int f4b = f4a + 16;
        float4 v0 = xp[f4a];
        float4 v1 = xp[f4b];
        float m = fmaxf(fmaxf(fmaxf(fabsf(v0.x), fabsf(v0.y)), fmaxf(fabsf(v0.z), fabsf(v0.w))),
                        fmaxf(fmaxf(fabsf(v1.x), fabsf(v1.y)), fmaxf(fabsf(v1.z), fabsf(v1.w))));
        #pragma unroll
        for (int off = 1; off < 16; off <<= 1)
            m = fmaxf(m, __shfl_xor(m, off, 16));
        const float s   = m * (1.0f / 127.0f);
        const float inv = (m > 0.0f) ? 127.0f / m : 0.0f;
        if (l == 0) scales[row] = s;
        auto q4 = [&](float4 v) -> unsigned {
            int a0 = (int)rintf(v.x * inv);
            int a1 = (int)rintf(v.y * inv);
            int a2 = (int)rintf(v.z * inv);
            int a3 = (int)rintf(v.w * inv);
            return (unsigned)(a0 & 0xff) | ((unsigned)(a1 & 0xff) << 8) |
                   ((unsigned)(a2 & 0xff) << 16) | ((unsigned)(a3 & 0xff) << 24);
        };
        ((unsigned*)x8)[f4a] = q4(v0);     // 4B dense int8 stores
        ((unsigned*)x8)[f4b] = q4(v1);
        ((uint2*)xb)[f4a] = pack4(v0);     // 8B dense bf16 stores
        ((uint2*)xb)[f4b] = pack4(v1);
    } else if (blockIdx.x < CONV2_BLOCKS + 16) {
        int flat = (blockIdx.x - CONV2_BLOCKS) * 256 + tid;   // 0..4095
        int k  = flat >> 4;
        int n0 = (flat & 15) * 8;
        const float* Wsrc = (k < 128) ? &Wl[k * 128 + n0] : &Wr[(k - 128) * 128 + n0];
        float4 a = *(const float4*)Wsrc;
        float4 b = *(const float4*)(Wsrc + 4);
        wT[(n0 + 0) * 256 + k] = f2bf(a.x);
        wT[(n0 + 1) * 256 + k] = f2bf(a.y);
        wT[(n0 + 2) * 256 + k] = f2bf(a.z);
        wT[(n0 + 3) * 256 + k] = f2bf(a.w);
        wT[(n0 + 4) * 256 + k] = f2bf(b.x);
        wT[(n0 + 5) * 256 + k] = f2bf(b.y);
        wT[(n0 + 6) * 256 + k] = f2bf(b.z);
        wT[(n0 + 7) * 256 + k] = f2bf(b.w);
    } else {
        int t3 = (blockIdx.x - CONV2_BLOCKS - 16) * 256 + tid;
        if (t3 < N_NODES / 4) ((uint4*)cnt)[t3] = make_uint4(0, 0, 0, 0);
    }
}

// ================= histogram, 4 edges/thread =================
__global__ __launch_bounds__(256) void hist4(
    const int* __restrict__ dst, int* __restrict__ cnt)
{
    int t = blockIdx.x * 256 + threadIdx.x;
    if (t < E4) {
        int e = t * 4;
        int4 d4 = *(const int4*)&dst[e];
        atomicAdd(&cnt[d4.x], 1);
        atomicAdd(&cnt[d4.y], 1);
        atomicAdd(&cnt[d4.z], 1);
        atomicAdd(&cnt[d4.w], 1);
    }
}

// ================= CSR scan / offsets / fill =================
__global__ __launch_bounds__(256) void scan_blocks(
    const int* __restrict__ cnt, int* __restrict__ ptr, int* __restrict__ bsums)
{
    __shared__ int sh[256];
    const int t = threadIdx.x;
    const int base = blockIdx.x * SCAN_CHUNK + t * 4;
    int v0 = (base + 0 < N_NODES) ? cnt[base + 0] : 0;
    int v1 = (base + 1 < N_NODES) ? cnt[base + 1] : 0;
    int v2 = (base + 2 < N_NODES) ? cnt[base + 2] : 0;
    int v3 = (base + 3 < N_NODES) ? cnt[base + 3] : 0;
    const int tsum = v0 + v1 + v2 + v3;
    sh[t] = tsum;
    __syncthreads();
    #pragma unroll
    for (int off = 1; off < 256; off <<= 1) {
        int val = (t >= off) ? sh[t - off] : 0;
        __syncthreads();
        sh[t] += val;
        __syncthreads();
    }
    const int texcl = sh[t] - tsum;
    if (t == 255) bsums[blockIdx.x] = sh[255];
    int e0 = texcl, e1 = e0 + v0, e2 = e1 + v1, e3 = e2 + v2;
    if (base + 0 < N_NODES) ptr[base + 0] = e0;
    if (base + 1 < N_NODES) ptr[base + 1] = e1;
    if (base + 2 < N_NODES) ptr[base + 2] = e2;
    if (base + 3 < N_NODES) ptr[base + 3] = e3;
}

__global__ __launch_bounds__(256) void add_offsets_fused(
    int* __restrict__ ptr, int* __restrict__ cursor, const int* __restrict__ bsums)
{
    __shared__ int sh[256];
    const int t = threadIdx.x;
    int v = (t < blockIdx.x) ? bsums[t] : 0;   // blockIdx.x <= 97 < 256
    sh[t] = v;
    __syncthreads();
    #pragma unroll
    for (int off = 128; off > 0; off >>= 1) {
        if (t < off) sh[t] += sh[t + off];
        __syncthreads();
    }
    const int soff = sh[0];
    const int base = blockIdx.x * SCAN_CHUNK + t * 4;
    #pragma unroll
    for (int j = 0; j < 4; ++j) {
        int i = base + j;
        if (i < N_NODES) {
            int p = ptr[i] + soff;
            ptr[i] = p;
            cursor[i] = p;
        }
    }
    if (blockIdx.x == 0 && t == 0) ptr[N_NODES] = N_EDGES;
}

__global__ __launch_bounds__(256) void csr_fill(
    const int* __restrict__ src, const int* __restrict__ dst,
    int* __restrict__ cursor, int* __restrict__ sorted_src)
{
    int t = blockIdx.x * 256 + threadIdx.x;
    if (t < E4) {
        int e = t * 4;
        int4 d4 = *(const int4*)&dst[e];
        int4 s4 = *(const int4*)&src[e];
        int p0 = atomicAdd(&cursor[d4.x], 1);
        int p1 = atomicAdd(&cursor[d4.y], 1);
        int p2 = atomicAdd(&cursor[d4.z], 1);
        int p3 = atomicAdd(&cursor[d4.w], 1);
        sorted_src[p0] = s4.x;
        sorted_src[p1] = s4.y;
        sorted_src[p2] = s4.z;
        sorted_src[p3] = s4.w;
    }
}

// ========== FUSED int8 gather-mean + bf16 MFMA GEMM (register-B) ==========
// One block per 32-row tile (3125 blocks).
// Phase 1a: stage bf16 x rows into sA x-half (slots 16..31).
// Phase 1b: 8 lanes/node (32 groups): gather int8 rows (16B/lane) + per-row
//           scale, mean in f32, pack bf16 into sA mean-half (slots 0..15).
// Phase 2: MFMA (B fragments loaded after barrier) + bias + out write.
__global__ __launch_bounds__(256) void sage_fused(
    const unsigned short* __restrict__ xb,
    const unsigned char* __restrict__ x8,
    const float* __restrict__ scales,
    const int* __restrict__ ptr,
    const int* __restrict__ sorted_src,
    const unsigned short* __restrict__ wT,
    const float* __restrict__ bl,
    float* __restrict__ out)
{
    __shared__ unsigned short sA[32 * 256];   // 16 KB

    const int tid  = threadIdx.x;
    const int lane = tid & 63;
    const int w    = tid >> 6;
    const int l15  = lane & 15;
    const int lg   = lane >> 4;

    const int row0 = blockIdx.x * 32;

    // ---- phase 1a: stage x-half (slots 16..31), 2 short8 chunks/thread ----
    #pragma unroll
    for (int i = 0; i < 2; ++i) {
        int c = tid + i * 256;          // 0..511
        int r = c >> 4;                 // 32 rows x 16 chunks
        int s = 16 + (c & 15);
        short8 v = *(const short8*)&xb[(size_t)(row0 + r) * D + (c & 15) * 8];
        *(short8*)&sA[r * 256 + ((s ^ (r & 7)) << 3)] = v;
    }

    // ---- phase 1b: int8 gather-mean, 8 lanes/node, one node per group ----
    {
        const int g = tid >> 3;          // 0..31 (row)
        const int l = tid & 7;
        const size_t off8 = (size_t)l * 16;   // byte offset in 128B int8 row
        const int node = row0 + g;
        const int beg = ptr[node];
        const int end = ptr[node + 1];

        float acc[4][16];
        #pragma unroll
        for (int a = 0; a < 4; ++a)
            #pragma unroll
            for (int j = 0; j < 16; ++j) acc[a][j] = 0.0f;

        for (int i = beg; i < end; i += 4) {
            int last = end - 1;
            int e1 = i + 1 < end ? i + 1 : last;
            int e2 = i + 2 < end ? i + 2 : last;
            int e3 = i + 3 < end ? i + 3 : last;
            float w1 = (i + 1 < end) ? 1.f : 0.f;
            float w2 = (i + 2 < end) ? 1.f : 0.f;
            float w3 = (i + 3 < end) ? 1.f : 0.f;
            int s0 = sorted_src[i],  s1 = sorted_src[e1];
            int s2 = sorted_src[e2], s3 = sorted_src[e3];
            uint4 q0 = *(const uint4*)&x8[(size_t)s0 * D + off8];
            uint4 q1 = *(const uint4*)&x8[(size_t)s1 * D + off8];
            uint4 q2 = *(const uint4*)&x8[(size_t)s2 * D + off8];
            uint4 q3 = *(const uint4*)&x8[(size_t)s3 * D + off8];
            float ws0 = scales[s0];
            float ws1 = w1 * scales[s1];
            float ws2 = w2 * scales[s2];
            float ws3 = w3 * scales[s3];

            float t[16];
            i8x4_to_f32(q0.x, &t[0]);  i8x4_to_f32(q0.y, &t[4]);
            i8x4_to_f32(q0.z, &t[8]);  i8x4_to_f32(q0.w, &t[12]);
            #pragma unroll
            for (int j = 0; j < 16; ++j) acc[0][j] = fmaf(ws0, t[j], acc[0][j]);

            i8x4_to_f32(q1.x, &t[0]);  i8x4_to_f32(q1.y, &t[4]);
            i8x4_to_f32(q1.z, &t[8]);  i8x4_to_f32(q1.w, &t[12]);
            #pragma unroll
            for (int j = 0; j < 16; ++j) acc[1][j] = fmaf(ws1, t[j], acc[1][j]);

            i8x4_to_f32(q2.x, &t[0]);  i8x4_to_f32(q2.y, &t[4]);
            i8x4_to_f32(q2.z, &t[8]);  i8x4_to_f32(q2.w, &t[12]);
            #pragma unroll
            for (int j = 0; j < 16; ++j) acc[2][j] = fmaf(ws2, t[j], acc[2][j]);

            i8x4_to_f32(q3.x, &t[0]);  i8x4_to_f32(q3.y, &t[4]);
            i8x4_to_f32(q3.z, &t[8]);  i8x4_to_f32(q3.w, &t[12]);
            #pragma unroll
            for (int j = 0; j < 16; ++j) acc[3][j] = fmaf(ws3, t[j], acc[3][j]);
        }

        const float sc = 1.0f / fmaxf((float)(end - beg), 1.0f);
        float m[16];
        #pragma unroll
        for (int j = 0; j < 16; ++j)
            m[j] = ((acc[0][j] + acc[1][j]) + (acc[2][j] + acc[3][j])) * sc;

        uint4 o_lo, o_hi;
        o_lo.x = (unsigned)f2bf(m[0])  | ((unsigned)f2bf(m[1])  << 16);
        o_lo.y = (unsigned)f2bf(m[2])  | ((unsigned)f2bf(m[3])  << 16);
        o_lo.z = (unsigned)f2bf(m[4])  | ((unsigned)f2bf(m[5])  << 16);
        o_lo.w = (unsigned)f2bf(m[6])  | ((unsigned)f2bf(m[7])  << 16);
        o_hi.x = (unsigned)f2bf(m[8])  | ((unsigned)f2bf(m[9])  << 16);
        o_hi.y = (unsigned)f2bf(m[10]) | ((unsigned)f2bf(m[11]) << 16);
        o_hi.z = (unsigned)f2bf(m[12]) | ((unsigned)f2bf(m[13]) << 16);
        o_hi.w = (unsigned)f2bf(m[14]) | ((unsigned)f2bf(m[15]) << 16);
        int s0s = 2 * l;              // slots 0..15 (mean half)
        int s1s = 2 * l + 1;
        *(uint4*)&sA[g * 256 + ((s0s ^ (g & 7)) << 3)] = o_lo;
        *(uint4*)&sA[g * 256 + ((s1s ^ (g & 7)) << 3)] = o_hi;
    }
    __syncthreads();

    // ---- phase 2: MFMA (B loaded here to keep gather-phase VGPRs low) ----
    const int n0 = w * 32 + l15;
    const int n1 = n0 + 16;
    short8 B0[8], B1[8];
    #pragma unroll
    for (int s = 0; s < 8; ++s) {
        B0[s] = *(const short8*)&wT[(size_t)n0 * 256 + s * 32 + lg * 8];
        B1[s] = *(const short8*)&wT[(size_t)n1 * 256 + s * 32 + lg * 8];
    }
    const float bias0 = bl[n0];
    const float bias1 = bl[n1];

    const int a_r0 = l15;
    const int a_r1 = 16 + l15;

    f32x4 acc00 = {0.f,0.f,0.f,0.f}, acc01 = {0.f,0.f,0.f,0.f};
    f32x4 acc10 = {0.f,0.f,0.f,0.f}, acc11 = {0.f,0.f,0.f,0.f};

    #pragma unroll
    for (int s = 0; s < 8; ++s) {
        int ks = s * 4 + lg;
        short8 a0 = *(const short8*)&sA[a_r0 * 256 + ((ks ^ (a_r0 & 7)) << 3)];
        short8 a1 = *(const short8*)&sA[a_r1 * 256 + ((ks ^ (a_r1 & 7)) << 3)];
        acc00 = __builtin_amdgcn_mfma_f32_16x16x32_bf16(a0, B0[s], acc00, 0, 0, 0);
        acc01 = __builtin_amdgcn_mfma_f32_16x16x32_bf16(a0, B1[s], acc01, 0, 0, 0);
        acc10 = __builtin_amdgcn_mfma_f32_16x16x32_bf16(a1, B0[s], acc10, 0, 0, 0);
        acc11 = __builtin_amdgcn_mfma_f32_16x16x32_bf16(a1, B1[s], acc11, 0, 0, 0);
    }

    // C layout: col=lane&15, row=(lane>>4)*4+reg (m89)
    #pragma unroll
    for (int reg = 0; reg < 4; ++reg) {
        int r0w = row0 + lg * 4 + reg;
        int r1w = r0w + 16;
        out[(size_t)r0w * D + n0] = acc00[reg] + bias0;
        out[(size_t)r0w * D + n1] = acc01[reg] + bias1;
        out[(size_t)r1w * D + n0] = acc10[reg] + bias0;
        out[(size_t)r1w * D + n1] = acc11[reg] + bias1;
    }
}

// ================= Path B: fp32 gather + convert-in-GEMM (LDS-B) ===========
__global__ __launch_bounds__(256) void wt_build(
    const float* __restrict__ Wl, const float* __restrict__ Wr,
    unsigned short* __restrict__ wT)
{
    int idx = blockIdx.x * 256 + threadIdx.x;
    if (idx >= 128 * 256) return;
    int n = idx >> 8;
    int k = idx & 255;
    float v = (k < 128) ? Wl[k * 128 + n] : Wr[(k - 128) * 128 + n];
    wT[n * 256 + k] = f2bf(v);
}

__global__ __launch_bounds__(256) void sage_aggregate(
    const float* __restrict__ x,
    const int* __restrict__ ptr,
    const int* __restrict__ sorted_src,
    float* __restrict__ mean)
{
    const int node = blockIdx.x * 4 + (threadIdx.x >> 6);
    if (node >= N_NODES) return;
    const int lane = threadIdx.x & 63;
    const int beg = ptr[node];
    const int end = ptr[node + 1];

    float2 acc0 = make_float2(0.f, 0.f);
    float2 acc1 = make_float2(0.f, 0.f);
    int i = beg;
    for (; i + 1 < end; i += 2) {
        int s0 = sorted_src[i];
        int s1 = sorted_src[i + 1];
        float2 a = *(const float2*)&x[(size_t)s0 * D + lane * 2];
        float2 b = *(const float2*)&x[(size_t)s1 * D + lane * 2];
        acc0.x += a.x; acc0.y += a.y;
        acc1.x += b.x; acc1.y += b.y;
    }
    if (i < end) {
        int s0 = sorted_src[i];
        float2 a = *(const float2*)&x[(size_t)s0 * D + lane * 2];
        acc0.x += a.x; acc0.y += a.y;
    }
    const float sc = 1.0f / fmaxf((float)(end - beg), 1.0f);
    float2 r = make_float2((acc0.x + acc1.x) * sc, (acc0.y + acc1.y) * sc);
    *(float2*)&mean[(size_t)node * D + lane * 2] = r;
}

__global__ __launch_bounds__(256) void sage_gemm_mfma(
    const float* __restrict__ x,
    const unsigned short* __restrict__ wT,
    const float* __restrict__ bl,
    float* __restrict__ out)
{
    __shared__ unsigned short sW[128 * 256];
    __shared__ unsigned short sA1[32 * 256];

    const int tid  = threadIdx.x;
    const int lane = tid & 63;
    const int w    = tid >> 6;
    const int l15  = lane & 15;
    const int lg   = lane >> 4;

    #pragma unroll
    for (int i = 0; i < 16; ++i) {
        int c  = tid + i * 256;
        int n  = c >> 5;
        int k8 = c & 31;
        short8 v = ((const short8*)wT)[c];
        *(short8*)&sW[n * 256 + ((k8 ^ (n & 7)) << 3)] = v;
    }

    const int a_r0 = l15;
    const int a_r1 = 16 + l15;
    const int n0 = w * 32 + l15;
    const int n1 = n0 + 16;
    const float bias0 = bl[n0];
    const float bias1 = bl[n1];
    const int nTiles = N_NODES / 32;

    for (int tile = blockIdx.x; tile < nTiles; tile += gridDim.x) {
        const int row0 = tile * 32;
        #pragma unroll
        for (int i = 0; i < 8; ++i) {
            int c    = tid + i * 256;
            int r    = c >> 6;
            int half = (c >> 5) & 1;
            int f4   = c & 31;
            const float* srcp = half ? &x[(size_t)(row0 + r) * D + f4 * 4]
                                     : &out[(size_t)(row0 + r) * D + f4 * 4];
            float4 v = *(const float4*)srcp;
            short4v b;
            b.x = (short)f2bf(v.x); b.y = (short)f2bf(v.y);
            b.z = (short)f2bf(v.z); b.w = (short)f2bf(v.w);
            int k = half * 128 + f4 * 4;
            int u = k >> 3;
            *(short4v*)&sA1[r * 256 + ((u ^ (r & 7)) << 3) + (k & 7)] = b;
        }
        __syncthreads();

        f32x4 acc00 = {0.f,0.f,0.f,0.f}, acc01 = {0.f,0.f,0.f,0.f};
        f32x4 acc10 = {0.f,0.f,0.f,0.f}, acc11 = {0.f,0.f,0.f,0.f};

        #pragma unroll
        for (int s = 0; s < 8; ++s) {
            int ks = s * 4 + lg;
            short8 a0 = *(const short8*)&sA1[a_r0 * 256 + ((ks ^ (a_r0 & 7)) << 3)];
            short8 a1 = *(const short8*)&sA1[a_r1 * 256 + ((ks ^ (a_r1 & 7)) << 3)];
            short8 b0 = *(const short8*)&sW[n0 * 256 + ((ks ^ (n0 & 7)) << 3)];
            short8 b1 = *(const short8*)&sW[n1 * 256 + ((ks ^ (n1 & 7)) << 3)];
            acc00 = __builtin_amdgcn_mfma_f32_16x16x32_bf16(a0, b0, acc00, 0, 0, 0);
            acc01 = __builtin_amdgcn_mfma_f32_16x16x32_bf16(a0, b1, acc01, 0, 0, 0);
            acc10 = __builtin_amdgcn_mfma_f32_16x16x32_bf16(a1, b0, acc10, 0, 0, 0);
            acc11 = __builtin_amdgcn_mfma_f32_16x16x32_bf16(a1, b1, acc11, 0, 0, 0);
        }
        __syncthreads();

        #pragma unroll
        for (int reg = 0; reg < 4; ++reg) {
            int r0w = row0 + lg * 4 + reg;
            int r1w = r0w + 16;
            out[(size_t)r0w * D + n0] = acc00[reg] + bias0;
            out[(size_t)r0w * D + n1] = acc01[reg] + bias1;
            out[(size_t)r1w * D + n0] = acc10[reg] + bias0;
            out[(size_t)r1w * D + n1] = acc11[reg] + bias1;
        }
    }
}

// ================= Path C: scatter fallback ================================
__global__ __launch_bounds__(256) void sage_scatter(
    const float* __restrict__ x, const int* __restrict__ src,
    const int* __restrict__ dst, float* __restrict__ agg, float* __restrict__ deg)
{
    int gid = blockIdx.x * 256 + threadIdx.x;
    int e = gid >> 7;
    if (e >= N_EDGES) return;
    int d = gid & 127;
    atomicAdd(&agg[(size_t)dst[e] * D + d], x[(size_t)src[e] * D + d]);
    if (d == 0) atomicAdd(&deg[dst[e]], 1.0f);
}

__global__ __launch_bounds__(256) void apply_mean(
    float* __restrict__ agg, const float* __restrict__ deg)
{
    int gid = blockIdx.x * 256 + threadIdx.x;
    int row = gid >> 5;
    if (row >= N_NODES) return;
    float sc = 1.0f / fmaxf(deg[row], 1.0f);
    float4 v = ((float4*)agg)[gid];
    v.x *= sc; v.y *= sc; v.z *= sc; v.w *= sc;
    ((float4*)agg)[gid] = v;
}

__device__ __forceinline__ void accum_tile(
    float acc[4][4], const float (*sWf)[D], const float (*srow)[D], int h, int j4)
{
    #pragma unroll 2
    for (int k = 0; k < D; k += 4) {
        float4 w0 = *(const float4*)&sWf[k + 0][j4];
        float4 w1 = *(const float4*)&sWf[k + 1][j4];
        float4 w2 = *(const float4*)&sWf[k + 2][j4];
        float4 w3 = *(const float4*)&sWf[k + 3][j4];
        #pragma unroll
        for (int r = 0; r < 4; ++r) {
            float4 a = *(const float4*)&srow[h + r * 8][k];
            acc[r][0] = fmaf(a.x, w0.x, fmaf(a.y, w1.x, fmaf(a.z, w2.x, fmaf(a.w, w3.x, acc[r][0]))));
            acc[r][1] = fmaf(a.x, w0.y, fmaf(a.y, w1.y, fmaf(a.z, w2.y, fmaf(a.w, w3.y, acc[r][1]))));
            acc[r][2] = fmaf(a.x, w0.z, fmaf(a.y, w1.z, fmaf(a.z, w2.z, fmaf(a.w, w3.z, acc[r][2]))));
            acc[r][3] = fmaf(a.x, w0.w, fmaf(a.y, w1.w, fmaf(a.z, w2.w, fmaf(a.w, w3.w, acc[r][3]))));
        }
    }
}

__global__ __launch_bounds__(256) void sage_gemm_f32(
    const float* __restrict__ x, const float* __restrict__ Wl,
    const float* __restrict__ bl, const float* __restrict__ Wr,
    float* __restrict__ out)
{
    __shared__ float sWf[D][D];
    __shared__ float srow[32][D];
    const int tid = threadIdx.x;
    const int j4 = (tid & 31) * 4;
    const int h  = tid >> 5;
    const int nTiles = (N_NODES + 31) / 32;
    const float4 bias = *(const float4*)(bl + j4);

    for (int tile = blockIdx.x; tile < nTiles; tile += gridDim.x) {
        const int row0 = tile * 32;
        float acc[4][4];
        #pragma unroll
        for (int r = 0; r < 4; ++r)
            #pragma unroll
            for (int c = 0; c < 4; ++c) acc[r][c] = 0.0f;

        __syncthreads();
        #pragma unroll
        for (int i = 0; i < 16; ++i)
            ((float4*)sWf)[tid + i * 256] = ((const float4*)Wl)[tid + i * 256];
        #pragma unroll
        for (int i = 0; i < 4; ++i) {
            int idx = tid + i * 256, r = idx >> 5, c = idx & 31, row = row0 + r;
            float4 v = make_float4(0.f,0.f,0.f,0.f);
            if (row < N_NODES) v = ((const float4*)out)[(size_t)row * 32 + c];
            ((float4*)srow)[idx] = v;
        }
        __syncthreads();
        accum_tile(acc, sWf, srow, h, j4);

        __syncthreads();
        #pragma unroll
        for (int i = 0; i < 16; ++i)
            ((float4*)sWf)[tid + i * 256] = ((const float4*)Wr)[tid + i * 256];
        #pragma unroll
        for (int i = 0; i < 4; ++i) {
            int idx = tid + i * 256, r = idx >> 5, c = idx & 31, row = row0 + r;
            float4 v = make_float4(0.f,0.f,0.f,0.f);
            if (row < N_NODES) v = ((const float4*)x)[(size_t)row * 32 + c];
            ((float4*)srow)[idx] = v;
        }
        __syncthreads();
        accum_tile(acc, sWf, srow, h, j4);

        #pragma unroll
        for (int r = 0; r < 4; ++r) {
            int row = row0 + h + r * 8;
            if (row < N_NODES) {
                float4 v = make_float4(acc[r][0] + bias.x, acc[r][1] + bias.y,
                                       acc[r][2] + bias.z, acc[r][3] + bias.w);
                *(float4*)(out + (size_t)row * D + j4) = v;
            }
        }
    }
}

extern "C" void kernel_launch(void* const* d_in, const int* in_sizes, int n_in,
                              void* d_out, int out_size, void* d_ws, size_t ws_size,
                              hipStream_t stream) {
    const float* x   = (const float*)d_in[0];
    const int*   ei  = (const int*)d_in[1];
    const float* Wl  = (const float*)d_in[2];
    const float* bl  = (const float*)d_in[3];
    const float* Wr  = (const float*)d_in[4];
    float* out = (float*)d_out;

    const int* src = ei;
    const int* dst = ei + N_EDGES;

    int* cnt    = (int*)d_ws;                    // N
    int* ptr    = cnt + N_NODES;                 // N+1
    int* cursor = ptr + N_NODES + 1;             // N
    int* bsums  = cursor + N_NODES;              // 128
    int* sorted = bsums + 128;                   // E
    size_t int_count = (size_t)(3 * N_NODES + 1 + 128 + N_EDGES);
    int_count = (int_count + 7) & ~(size_t)7;    // 32B-align what follows
    unsigned short* wT = (unsigned short*)((int*)d_ws + int_count);  // 128*256 bf16
    unsigned short* xb = wT + 128 * 256;                             // N*D bf16
    unsigned char*  x8 = (unsigned char*)(xb + (size_t)N_NODES * D); // N*D int8
    float* scales      = (float*)(x8 + (size_t)N_NODES * D);         // N f32

    size_t need_B = int_count * sizeof(int);
    size_t need_A = need_B + 128 * 256 * 2 + (size_t)N_NODES * D * 2
                    + (size_t)N_NODES * D + (size_t)N_NODES * 4;  // wT+xb+x8+scales

    if (ws_size >= need_A) {
        conv_all<<<CONV2_BLOCKS + 16 + ZERO_BLOCKS, 256, 0, stream>>>(
            x, Wl, Wr, xb, x8, scales, wT, cnt);
        hist4<<<(E4 + 255) / 256, 256, 0, stream>>>(dst, cnt);
        scan_blocks<<<N_SCAN_BLOCKS, 256, 0, stream>>>(cnt, ptr, bsums);
        add_offsets_fused<<<N_SCAN_BLOCKS, 256, 0, stream>>>(ptr, cursor, bsums);
        csr_fill<<<(E4 + 255) / 256, 256, 0, stream>>>(src, dst, cursor, sorted);
        sage_fused<<<N_NODES / 32, 256, 0, stream>>>(
            xb, x8, scales, ptr, sorted, wT, bl, out);
    } else if (ws_size >= need_B) {
        hipMemsetAsync(cnt, 0, (size_t)N_NODES * sizeof(int), stream);
        hist4<<<(E4 + 255) / 256, 256, 0, stream>>>(dst, cnt);
        scan_blocks<<<N_SCAN_BLOCKS, 256, 0, stream>>>(cnt, ptr, bsums);
        add_offsets_fused<<<N_SCAN_BLOCKS, 256, 0, stream>>>(ptr, cursor, bsums);
        csr_fill<<<(E4 + 255) / 256, 256, 0, stream>>>(src, dst, cursor, sorted);
        unsigned short* wTc = (unsigned short*)cursor;   // cursor dead after fill
        wt_build<<<(128 * 256 + 255) / 256, 256, 0, stream>>>(Wl, Wr, wTc);
        sage_aggregate<<<(N_NODES + 3) / 4, 256, 0, stream>>>(x, ptr, sorted, out);
        sage_gemm_mfma<<<512, 256, 0, stream>>>(x, wTc, bl, out);
    } else {
        float* deg = (float*)d_ws;
        hipMemsetAsync(out, 0, (size_t)N_NODES * D * sizeof(float), stream);
        hipMemsetAsync(deg, 0, (size_t)N_NODES * sizeof(float), stream);
        long long total = (long long)N_EDGES * 128;
        sage_scatter<<<(int)((total + 255) / 256), 256, 0, stream>>>(x, src, dst, out, deg);
        apply_mean<<<(N_NODES * 32 + 255) / 256, 256, 0, stream>>>(out, deg);
        sage_gemm_f32<<<512, 256, 0, stream>>>(x, Wl, bl, Wr, out);
    }
}